// Round 8
// baseline (160.549 us; speedup 1.0000x reference)
//
#include <hip/hip_runtime.h>

#define GAMMA 0.99f
#define LAM   0.95f

constexpr int SEG   = 256;     // columns per segment (one wave's tile)
constexpr int WPB   = 4;       // waves per block
constexpr int BLOCK = WPB * 64;

// Segment affine map: g_at_segment_start = A + M * g_in_from_right.
// Both kernels compute the per-wave suffix scan identically, so the
// two-phase composition is numerically IDENTICAL to the R7 fused kernel
// (same ops, same order -> same absmax).

__device__ __forceinline__ void seg_delta_c(
    const float* __restrict__ rewards, const float* __restrict__ values,
    const float* __restrict__ next_value, const int* __restrict__ done,
    int row, int seg, int lane, int T,
    float delta[4], float c[4], float4& vv_out)
{
    const long rowbase = (long)row * T;
    const int  col0    = seg * SEG + lane * 4;

    const float4 rv = *reinterpret_cast<const float4*>(rewards + rowbase + col0);
    const float4 vv = *reinterpret_cast<const float4*>(values  + rowbase + col0);
    const int4   dv = *reinterpret_cast<const int4*>(done      + rowbase + col0);

    // boundary at segment end: values[E]/done[E]; at E==T bootstrap
    // next_value and done clamps to own last element (reference semantics).
    float bv = 0.0f; float bd = 0.0f;
    if (lane == 63) {
        const int E = seg * SEG + SEG;
        if (E < T) { bv = values[rowbase + E]; bd = (float)done[rowbase + E]; }
        else       { bv = next_value[row];     bd = (float)dv.w; }
    }
    const float v_nb = __shfl_down(vv.x, 1);
    const float d_nb = (float)__shfl_down(dv.x, 1);
    const float vnext = (lane == 63) ? bv : v_nb;
    const float dnext = (lane == 63) ? bd : d_nb;

    const float n0 = 1.0f - (float)dv.y;
    const float n1 = 1.0f - (float)dv.z;
    const float n2 = 1.0f - (float)dv.w;
    const float n3 = 1.0f - dnext;
    delta[0] = rv.x + GAMMA * vv.y  * n0 - vv.x;
    delta[1] = rv.y + GAMMA * vv.z  * n1 - vv.y;
    delta[2] = rv.z + GAMMA * vv.w  * n2 - vv.z;
    delta[3] = rv.w + GAMMA * vnext * n3 - vv.w;
    c[0] = (GAMMA * LAM) * n0;
    c[1] = (GAMMA * LAM) * n1;
    c[2] = (GAMMA * LAM) * n2;
    c[3] = (GAMMA * LAM) * n3;
    vv_out = vv;
}

// 64-lane inclusive suffix scan of affine fns (self ∘ higher-lane).
__device__ __forceinline__ void suffix_scan(int lane, float& sa, float& sm)
{
#pragma unroll
    for (int d = 1; d < 64; d <<= 1) {
        float oa = __shfl_down(sa, d);
        float om = __shfl_down(sm, d);
        if (lane + d < 64) { sa = sa + sm * oa; sm = sm * om; }
    }
}

// ---- phase 1: pure read-stream; write one (A,M) per segment ----
__global__ __launch_bounds__(BLOCK) void gae_sum_kernel(
    const float* __restrict__ rewards, const float* __restrict__ values,
    const float* __restrict__ next_value, const int* __restrict__ done,
    float2* __restrict__ summ,          // [B][S]
    int B, int T)
{
    const int S    = T / SEG;
    const int gw   = blockIdx.x * WPB + (threadIdx.x >> 6);
    const int lane = threadIdx.x & 63;
    if (gw >= B * S) return;            // wave-uniform
    const int row = gw / S, seg = gw % S;

    float delta[4], c[4]; float4 vv;
    seg_delta_c(rewards, values, next_value, done, row, seg, lane, T, delta, c, vv);

    float a = 0.0f, m = 1.0f;
#pragma unroll
    for (int j = 3; j >= 0; --j) { a = delta[j] + c[j] * a; m = c[j] * m; }

    float sa = a, sm = m;
    suffix_scan(lane, sa, sm);
    if (lane == 0) summ[(long)row * S + seg] = make_float2(sa, sm);
}

// ---- phase 2: re-read (L3-warm), apply cross-segment prefix, store ----
__global__ __launch_bounds__(BLOCK) void gae_apply_kernel(
    const float* __restrict__ rewards, const float* __restrict__ values,
    const float* __restrict__ next_value, const int* __restrict__ done,
    const float2* __restrict__ summ,
    float* __restrict__ adv_out, float* __restrict__ ret_out,
    int B, int T)
{
    const int S    = T / SEG;
    const int gw   = blockIdx.x * WPB + (threadIdx.x >> 6);
    const int lane = threadIdx.x & 63;
    if (gw >= B * S) return;            // wave-uniform
    const int row = gw / S, seg = gw % S;

    float delta[4], c[4]; float4 vv;
    seg_delta_c(rewards, values, next_value, done, row, seg, lane, T, delta, c, vv);

    float a = 0.0f, m = 1.0f;
#pragma unroll
    for (int j = 3; j >= 0; --j) { a = delta[j] + c[j] * a; m = c[j] * m; }

    float sa = a, sm = m;
    suffix_scan(lane, sa, sm);
    float ea = __shfl_down(sa, 1);      // exclusive-within-wave
    float em = __shfl_down(sm, 1);
    if (lane == 63) { ea = 0.0f; em = 1.0f; }

    // cross-segment prefix: compose summaries of segments to the right
    // (wave-uniform addresses; same op order as R7's cross-pass g chain).
    float g = 0.0f;
    const float2* rs = summ + (long)row * S;
    for (int j = S - 1; j > seg; --j) {
        const float2 s = rs[j];
        g = s.x + s.y * g;
    }
    float gin = ea + em * g;

#pragma unroll
    for (int j = 3; j >= 0; --j) {
        gin = delta[j] + c[j] * gin;
        delta[j] = gin;                 // delta[] now holds advantages
    }

    const long rowbase = (long)row * T;
    const int  col0    = seg * SEG + lane * 4;
    float4* a4 = reinterpret_cast<float4*>(adv_out + rowbase + col0);
    float4* t4 = reinterpret_cast<float4*>(ret_out + rowbase + col0);
    *a4 = make_float4(delta[0], delta[1], delta[2], delta[3]);
    *t4 = make_float4(delta[0] + vv.x, delta[1] + vv.y,
                      delta[2] + vv.z, delta[3] + vv.w);
}

// Fallback: one thread per row, sequential (any shape / tiny workspace).
__global__ void gae_naive_kernel(
    const float* __restrict__ rewards,
    const float* __restrict__ values,
    const float* __restrict__ next_value,
    const int*   __restrict__ done,
    float* __restrict__ adv_out,
    float* __restrict__ ret_out,
    int B, int T)
{
    int row = blockIdx.x * blockDim.x + threadIdx.x;
    if (row >= B) return;
    long base = (long)row * T;
    float g = 0.0f;
    for (int t = T - 1; t >= 0; --t) {
        int dcol = (t + 1 < T) ? (t + 1) : (T - 1);
        float nnt = 1.0f - (float)done[base + dcol];
        float nv  = (t + 1 < T) ? values[base + t + 1] : next_value[row];
        float dl  = rewards[base + t] + GAMMA * nv * nnt - values[base + t];
        g = dl + (GAMMA * LAM) * nnt * g;
        adv_out[base + t] = g;
        ret_out[base + t] = g + values[base + t];
    }
}

extern "C" void kernel_launch(void* const* d_in, const int* in_sizes, int n_in,
                              void* d_out, int out_size, void* d_ws, size_t ws_size,
                              hipStream_t stream) {
    const float* rewards    = (const float*)d_in[0];
    const float* values     = (const float*)d_in[1];
    const float* next_value = (const float*)d_in[2];
    const int*   done       = (const int*)d_in[3];

    const int B = in_sizes[2];               // next_value is [B]
    const int T = in_sizes[0] / B;           // rewards is [B, T]

    float* adv = (float*)d_out;
    float* ret = adv + (long)B * T;

    const long   nseg     = (T % SEG == 0) ? (long)B * (T / SEG) : 0;
    const size_t ws_need  = (size_t)nseg * sizeof(float2);

    if (nseg > 0 && ws_size >= ws_need) {
        float2* summ = (float2*)d_ws;
        const int blocks = (int)((nseg + WPB - 1) / WPB);
        gae_sum_kernel<<<blocks, BLOCK, 0, stream>>>(
            rewards, values, next_value, done, summ, B, T);
        gae_apply_kernel<<<blocks, BLOCK, 0, stream>>>(
            rewards, values, next_value, done, summ, adv, ret, B, T);
    } else {
        gae_naive_kernel<<<(B + 255) / 256, 256, 0, stream>>>(
            rewards, values, next_value, done, adv, ret, B, T);
    }
}